// Round 10
// baseline (4207.820 us; speedup 1.0000x reference)
//
#include <hip/hip_runtime.h>
#include <hip/hip_bf16.h>
#include <math.h>

#define NBANDS 400
#define NPIX   65536
#define FFW    128
#define KSEL   10
#define TOK    16    // tokens per WG
#define HS     403   // h LDS row stride (doubles)
#define FS     131   // f LDS row stride (doubles)

typedef double f64x4 __attribute__((ext_vector_type(4)));
#define MFMA64(a,b,c) __builtin_amdgcn_mfma_f64_16x16x4f64((a),(b),(c),0,0,0)

// ---- ws byte offsets ----
static constexpr size_t WSB_WVOT = 0;          // fp64 [2][400][400]  WvoT[l][k][j] = (Wo@Wv)[j][k]
static constexpr size_t WSB_BVO  = 2560000;    // fp64 [2][400]       Wo@bv + bo
static constexpr size_t WSB_SIG  = 2566400;    // fp64 [400]          sigmoid(band_importance)
static constexpr size_t WSB_W1T  = 2569600;    // fp32 [2][400][128]  W1T[l][k][jf] = W1[l][jf][k]
static constexpr size_t WSB_W2T  = 2979200;    // fp32 [2][128][400]  W2T[l][kf][j] = W2[l][j][kf]
static constexpr size_t WS_NEED  = 3388800;

// ---- out offsets (fp32 elements) ----
static constexpr size_t REC_OFF = 0;
static constexpr size_t IDX_OFF = 26214400;             // 400*65536
static constexpr size_t SCO_OFF = IDX_OFF + 655360;     // + 65536*10
static constexpr size_t SEL_OFF = SCO_OFF + 26214400;
static constexpr int    OUT_EXPECT = 53739520;

// ---------------- prep kernels ----------------

__global__ void prep_wvot(const float* __restrict__ Wv, const float* __restrict__ Wo,
                          double* __restrict__ WvoT) {
    int b = blockIdx.x;              // l*400 + j
    int l = b / 400, j = b - l * 400;
    int k = threadIdx.x;
    if (k >= 400) return;
    const float* wo = Wo + l * 160000 + j * 400;
    const float* wv = Wv + l * 160000;
    double acc = 0.0;
    #pragma unroll 4
    for (int m = 0; m < 400; ++m)
        acc += (double)wo[m] * (double)wv[m * 400 + k];
    WvoT[l * 160000 + k * 400 + j] = acc;
}

__global__ void prep_transpose(const float* __restrict__ W1, const float* __restrict__ W2,
                               float* __restrict__ W1T, float* __restrict__ W2T) {
    int idx = blockIdx.x * blockDim.x + threadIdx.x;
    if (idx < 2 * FFW * NBANDS) {
        int l = idx / (FFW * NBANDS); int r = idx - l * (FFW * NBANDS);
        int jf = r / NBANDS; int k = r - jf * NBANDS;
        W1T[l * FFW * NBANDS + k * FFW + jf] = W1[idx];      // exact value copy
        int j = r / FFW; int kf = r - j * FFW;
        W2T[l * FFW * NBANDS + kf * NBANDS + j] = W2[idx];   // exact value copy
    }
}

__global__ void prep_small(const float* __restrict__ Wo, const float* __restrict__ bv,
                           const float* __restrict__ bo, const float* __restrict__ bi,
                           double* __restrict__ bvo, double* __restrict__ sigd) {
    int g = blockIdx.x * blockDim.x + threadIdx.x;
    if (g < 800) {
        int l = g / 400;
        const float* wo = Wo + l * 160000 + (g - l * 400) * 400;
        const float* bb = bv + l * 400;
        double acc = (double)bo[g];
        for (int m = 0; m < 400; ++m) acc += (double)wo[m] * (double)bb[m];
        bvo[g] = acc;
    } else if (g < 1200) {
        int c = g - 800;
        sigd[c] = 1.0 / (1.0 + exp(-(double)bi[c]));
    }
}

__global__ void sentinel_kernel(float* out, float v) {
    out[blockIdx.x * 256 + threadIdx.x] = v;   // diagnostic marker
}

// ---------------- main kernel ----------------
// r8 structure (16 tokens/WG, 512 threads = 8 waves, 2 WGs/CU) + manual
// software pipelining: each GEMM k-loop prefetches iteration k+4's A/B
// operands into registers BEFORE issuing iteration k's MFMAs (explicit
// load->use distance of ~1 iteration covers L2 hit latency). FF1 uses 2
// alternating accumulators to break its serial MFMA dependency chain.
// D write-back slots SELF-CALIBRATED at runtime (probe MFMAs).
// LDS dbl: h 16*403=6448, f 16*131=2096, red 64, lval 160, sigs 400,
// d1s 72(eq), lidx 80(eq) => 74560 B -> 2 WGs/CU.

__device__ inline void layer_norm_inplace(double* __restrict__ h, double* __restrict__ red,
                                          const float* __restrict__ w, const float* __restrict__ b,
                                          int tid) {
    {
        int t = tid >> 5, q = tid & 31;       // 16 tokens x 32 lanes
        double s = 0.0, ss = 0.0;
        for (int j = q; j < NBANDS; j += 32) {
            double v = h[t * HS + j]; s += v; ss += v * v;
        }
        #pragma unroll
        for (int m = 1; m < 32; m <<= 1) {
            s  += __shfl_xor(s, m, 64);
            ss += __shfl_xor(ss, m, 64);
        }
        if (q == 0) { red[t * 2] = s; red[t * 2 + 1] = ss; }
    }
    __syncthreads();
    for (int idx = tid; idx < TOK * NBANDS; idx += 512) {
        int t = idx / NBANDS, j = idx - t * NBANDS;
        double mu  = red[t * 2] / 400.0;
        double var = red[t * 2 + 1] / 400.0 - mu * mu;
        double rs  = 1.0 / sqrt(var + 1e-5);
        h[t * HS + j] = (h[t * HS + j] - mu) * rs * (double)w[j] + (double)b[j];
    }
    __syncthreads();
}

__global__ __launch_bounds__(512) void hbsm_main(
    const float* __restrict__ x, const float* __restrict__ xo,
    const float* __restrict__ pos,
    const float* __restrict__ ln1w, const float* __restrict__ ln1b,
    const float* __restrict__ b1,   const float* __restrict__ b2,
    const float* __restrict__ ln2w, const float* __restrict__ ln2b,
    const float* __restrict__ We1,  const float* __restrict__ be1,
    const float* __restrict__ We2,  const float* __restrict__ be2,
    const float* __restrict__ Wd1,  const float* __restrict__ bd1,
    const float* __restrict__ Wd2,  const float* __restrict__ bd2,
    const double* __restrict__ WvoT, const double* __restrict__ bvo,
    const double* __restrict__ sigd,
    const float* __restrict__ W1Tf,  const float* __restrict__ W2Tf,
    float* __restrict__ out)
{
    extern __shared__ double smem[];
    double* h    = smem;                    // 16*403
    double* f    = h + TOK * HS;            // 16*131
    double* red  = f + TOK * FS;            // 64
    double* lval = red + 64;                // 160
    double* sigs = lval + 160;              // 400
    float*  d1s  = (float*)(sigs + 400);    // 144 f32
    int*    lidx = (int*)(d1s + 144);       // 160 i32

    const int tid  = threadIdx.x;
    const int p0   = blockIdx.x * TOK;
    const int lane = tid & 63;
    const int wv   = tid >> 6;              // wave 0..7
    const int rA   = lane & 15;             // A-load row / B-load col
    const int kq   = lane >> 4;             // k quarter (assumed, cancels if wrong)

    // ---- D-slot self-calibration ----
    int rowm[4], colm[4];
    {
        f64x4 z = {0.0, 0.0, 0.0, 0.0};
        f64x4 pr = MFMA64(0.25 * (double)rA, 1.0, z);   // D[i][j] = i
        f64x4 pc = MFMA64(0.25, (double)rA, z);         // D[i][j] = j
        #pragma unroll
        for (int i = 0; i < 4; ++i) {
            rowm[i] = ((int)(pr[i] + 0.5)) & 15;
            colm[i] = ((int)(pc[i] + 0.5)) & 15;
        }
    }

    for (int i = tid; i < NBANDS; i += 512) sigs[i] = sigd[i];
    for (int i = tid; i < TOK * NBANDS; i += 512) {
        int t = i & 15, c = i >> 4;
        h[t * HS + c] = (double)x[(size_t)c * NPIX + p0 + t] + (double)pos[c];
    }
    __syncthreads();

    const double* hA = h + rA * HS;
    const int c0 = wv * 16 + rA, c1 = c0 + 128, c2 = c0 + 256;
    const int ct = 384 + rA;
    const bool xtraA = (wv == 0);           // attn tail tile owner
    const bool xtraF = (wv == 4);           // FF2 tail tile owner

    for (int l = 0; l < 2; ++l) {
        // ---- attention: h += h @ WvoT + bvo ; LN1  (prefetched pipeline) ----
        {
            const double* WT  = WvoT + l * 160000;
            const double* bb0 = bvo + l * 400;
            f64x4 a0={0,0,0,0}, a1={0,0,0,0}, a2={0,0,0,0}, a3={0,0,0,0};
            // prologue: loads for k0 = 0
            double av = hA[kq];
            const double* wr0 = WT + (size_t)kq * 400;
            double b0 = wr0[c0], b1v = wr0[c1], b2v = wr0[c2];
            double bt = xtraA ? wr0[ct] : 0.0;
            for (int k0 = 0; k0 < NBANDS; k0 += 4) {
                const int kn = (k0 + 4 < NBANDS) ? k0 + 4 : k0;   // last iter: dup (harmless)
                // issue next-iteration loads BEFORE this iteration's MFMAs
                double av_n = hA[kn + kq];
                const double* wrn = WT + (size_t)(kn + kq) * 400;
                double b0_n = wrn[c0], b1_n = wrn[c1], b2_n = wrn[c2];
                double bt_n = xtraA ? wrn[ct] : 0.0;
                a0 = MFMA64(av, b0, a0);
                a1 = MFMA64(av, b1v, a1);
                a2 = MFMA64(av, b2v, a2);
                if (xtraA) a3 = MFMA64(av, bt, a3);
                av = av_n; b0 = b0_n; b1v = b1_n; b2v = b2_n; bt = bt_n;
            }
            __syncthreads();      // all A-reads of h complete before in-place update
            #pragma unroll
            for (int i = 0; i < 4; ++i) {
                int r  = rowm[i];
                int j0 = wv * 16 + colm[i], j1 = j0 + 128, j2 = j0 + 256;
                h[r * HS + j0] += a0[i] + bb0[j0];
                h[r * HS + j1] += a1[i] + bb0[j1];
                h[r * HS + j2] += a2[i] + bb0[j2];
                if (xtraA) {
                    int jt = 384 + colm[i];
                    h[r * HS + jt] += a3[i] + bb0[jt];
                }
            }
            __syncthreads();
        }
        layer_norm_inplace(h, red, ln1w + l * 400, ln1b + l * 400, tid);

        // ---- FF1: f = relu(h @ W1T + b1)  (2 alternating acc chains) ----
        {
            const float* WT  = W1Tf + (size_t)l * 51200;
            const float* bb1 = b1 + l * FFW;
            const int cf = wv * 16 + rA;
            f64x4 e0 = {0,0,0,0}, e1 = {0,0,0,0};
            double av = hA[kq];
            double bw = (double)WT[(size_t)kq * FFW + cf];
            for (int k0 = 0; k0 < NBANDS; k0 += 4) {
                const int kn = (k0 + 4 < NBANDS) ? k0 + 4 : k0;
                double av_n = hA[kn + kq];
                double bw_n = (double)WT[(size_t)(kn + kq) * FFW + cf];
                if ((k0 >> 2) & 1) e1 = MFMA64(av, bw, e1);
                else               e0 = MFMA64(av, bw, e0);
                av = av_n; bw = bw_n;
            }
            #pragma unroll
            for (int i = 0; i < 4; ++i) {
                int r  = rowm[i];
                int jf = wv * 16 + colm[i];
                double v0 = e0[i] + e1[i] + (double)bb1[jf];
                f[r * FS + jf] = v0 > 0.0 ? v0 : 0.0;
            }
            __syncthreads();   // f writes visible (also fences FF1's h reads)
        }

        // ---- FF2: h += f @ W2T + b2 ; LN2  (prefetched pipeline) ----
        {
            const float* WT  = W2Tf + (size_t)l * 51200;
            const float* bb2 = b2 + l * 400;
            const double* fA = f + rA * FS;
            f64x4 a0={0,0,0,0}, a1={0,0,0,0}, a2={0,0,0,0}, a3={0,0,0,0};
            double av = fA[kq];
            const float* wr0 = WT + (size_t)kq * 400;
            double b0 = (double)wr0[c0], b1v = (double)wr0[c1], b2v = (double)wr0[c2];
            double bt = xtraF ? (double)wr0[ct] : 0.0;
            for (int k0 = 0; k0 < FFW; k0 += 4) {
                const int kn = (k0 + 4 < FFW) ? k0 + 4 : k0;
                double av_n = fA[kn + kq];
                const float* wrn = WT + (size_t)(kn + kq) * 400;
                double b0_n = (double)wrn[c0], b1_n = (double)wrn[c1], b2_n = (double)wrn[c2];
                double bt_n = xtraF ? (double)wrn[ct] : 0.0;
                a0 = MFMA64(av, b0, a0);
                a1 = MFMA64(av, b1v, a1);
                a2 = MFMA64(av, b2v, a2);
                if (xtraF) a3 = MFMA64(av, bt, a3);
                av = av_n; b0 = b0_n; b1v = b1_n; b2v = b2_n; bt = bt_n;
            }
            // h is not read during FF2 (A comes from f); owner-disjoint writes safe
            #pragma unroll
            for (int i = 0; i < 4; ++i) {
                int r  = rowm[i];
                int j0 = wv * 16 + colm[i], j1 = j0 + 128, j2 = j0 + 256;
                h[r * HS + j0] += a0[i] + (double)bb2[j0];
                h[r * HS + j1] += a1[i] + (double)bb2[j1];
                h[r * HS + j2] += a2[i] + (double)bb2[j2];
                if (xtraF) {
                    int jt = 384 + colm[i];
                    h[r * HS + jt] += a3[i] + (double)bb2[jt];
                }
            }
            __syncthreads();
        }
        layer_norm_inplace(h, red, ln2w + l * 400, ln2b + l * 400, tid);
    }

    // ---- attention scores output (fp32) ----
    for (int idx = tid; idx < TOK * NBANDS; idx += 512) {
        int t = idx / NBANDS, c = idx - t * NBANDS;
        out[SCO_OFF + (size_t)(p0 + t) * NBANDS + c] = (float)(h[t * HS + c] * sigs[c]);
    }

    // ---- top-k, gather, encoder/decoder front (1 thread per token) ----
    if (tid < TOK) {
        int t = tid;
        double* lv = lval + t * KSEL;
        int*    li = lidx + t * KSEL;
        #pragma unroll
        for (int k = 0; k < KSEL; ++k) { lv[k] = -1.0e300; li[k] = 0; }
        for (int c = 0; c < NBANDS; ++c) {
            double v = h[t * HS + c] * sigs[c];
            if (v > lv[KSEL - 1]) {           // strict > keeps earlier index on ties
                int j = KSEL - 1;
                while (j > 0 && lv[j - 1] < v) {
                    lv[j] = lv[j - 1]; li[j] = li[j - 1]; --j;
                }
                lv[j] = v; li[j] = c;
            }
        }
        for (int a = 1; a < KSEL; ++a) {      // sort by band index ascending
            double v = lv[a]; int ci = li[a];
            int bq = a - 1;
            while (bq >= 0 && li[bq] > ci) {
                lv[bq + 1] = lv[bq]; li[bq + 1] = li[bq]; --bq;
            }
            lv[bq + 1] = v; li[bq + 1] = ci;
        }
        double sel[KSEL];
        #pragma unroll
        for (int k = 0; k < KSEL; ++k) {
            int ci = li[k];
            float band = xo[(size_t)ci * NPIX + p0 + t];
            out[IDX_OFF + (size_t)(p0 + t) * KSEL + k] = (float)ci;
            out[SEL_OFF + (size_t)(p0 + t) * KSEL + k] = band;
            sel[k] = (double)band * lv[k];
        }
        double e1[8], e2[8];
        #pragma unroll
        for (int e = 0; e < 8; ++e) {
            double acc = (double)be1[e];
            #pragma unroll
            for (int k = 0; k < KSEL; ++k) acc += sel[k] * (double)We1[e * KSEL + k];
            e1[e] = acc > 0.0 ? acc : 0.0;
        }
        #pragma unroll
        for (int e = 0; e < 8; ++e) {
            double acc = (double)be2[e];
            #pragma unroll
            for (int j = 0; j < 8; ++j) acc += e1[j] * (double)We2[e * 8 + j];
            e2[e] = acc;
        }
        #pragma unroll
        for (int e = 0; e < 8; ++e) {
            double acc = (double)bd1[e];
            #pragma unroll
            for (int j = 0; j < 8; ++j) acc += e2[j] * (double)Wd1[e * 8 + j];
            d1s[t * 9 + e] = (float)(acc > 0.0 ? acc : 0.0);
        }
    }
    __syncthreads();

    // ---- decode + reconstructed output (coalesced over tokens, fp32) ----
    for (int idx = tid; idx < TOK * NBANDS; idx += 512) {
        int t = idx & 15, c = idx >> 4;
        double acc = (double)bd2[c];
        const float* w = Wd2 + c * 8;
        #pragma unroll
        for (int e = 0; e < 8; ++e) acc += (double)d1s[t * 9 + e] * (double)w[e];
        out[REC_OFF + (size_t)c * NPIX + p0 + t] = (float)acc;
    }
}

// ---------------- launch ----------------
extern "C" void kernel_launch(void* const* d_in, const int* in_sizes, int n_in,
                              void* d_out, int out_size, void* d_ws, size_t ws_size,
                              hipStream_t stream) {
    if (ws_size < WS_NEED) {   // diagnostic: ws too small -> error ~777
        sentinel_kernel<<<dim3(256), dim3(256), 0, stream>>>((float*)d_out, -777.0f);
        return;
    }
    if (out_size != OUT_EXPECT) {  // diagnostic: unexpected out layout -> error ~1e6
        sentinel_kernel<<<dim3(1), dim3(1), 0, stream>>>((float*)d_out, 1.0e6f);
        return;
    }
    const float* x    = (const float*)d_in[0];
    const float* xo   = (const float*)d_in[1];
    const float* pos  = (const float*)d_in[2];
    const float* bi   = (const float*)d_in[3];
    const float* Wv   = (const float*)d_in[4];
    const float* bv   = (const float*)d_in[5];
    const float* Wo   = (const float*)d_in[6];
    const float* bo   = (const float*)d_in[7];
    const float* ln1w = (const float*)d_in[8];
    const float* ln1b = (const float*)d_in[9];
    const float* W1   = (const float*)d_in[10];
    const float* b1   = (const float*)d_in[11];
    const float* W2   = (const float*)d_in[12];
    const float* b2   = (const float*)d_in[13];
    const float* ln2w = (const float*)d_in[14];
    const float* ln2b = (const float*)d_in[15];
    const float* We1  = (const float*)d_in[16];
    const float* be1  = (const float*)d_in[17];
    const float* We2  = (const float*)d_in[18];
    const float* be2  = (const float*)d_in[19];
    const float* Wd1  = (const float*)d_in[20];
    const float* bd1  = (const float*)d_in[21];
    const float* Wd2  = (const float*)d_in[22];
    const float* bd2  = (const float*)d_in[23];

    char* wsb = (char*)d_ws;
    double* WvoT = (double*)(wsb + WSB_WVOT);
    double* bvo  = (double*)(wsb + WSB_BVO);
    double* sigd = (double*)(wsb + WSB_SIG);
    float*  W1Tf = (float*)(wsb + WSB_W1T);
    float*  W2Tf = (float*)(wsb + WSB_W2T);

    prep_wvot<<<dim3(800), dim3(512), 0, stream>>>(Wv, Wo, WvoT);
    prep_transpose<<<dim3(400), dim3(256), 0, stream>>>(W1, W2, W1Tf, W2Tf);
    prep_small<<<dim3(5), dim3(256), 0, stream>>>(Wo, bv, bo, bi, bvo, sigd);

    const int smem_bytes = 74560;
    hipFuncSetAttribute((const void*)hbsm_main,
                        hipFuncAttributeMaxDynamicSharedMemorySize, smem_bytes);
    hipLaunchKernelGGL(hbsm_main, dim3(4096), dim3(512), smem_bytes, stream,
                       x, xo, pos, ln1w, ln1b, b1, b2, ln2w, ln2b,
                       We1, be1, We2, be2, Wd1, bd1, Wd2, bd2,
                       WvoT, bvo, sigd, W1Tf, W2Tf, (float*)d_out);
    (void)in_sizes; (void)n_in;
}

// Round 11
// 2676.558 us; speedup vs baseline: 1.5721x; 1.5721x over previous
//
#include <hip/hip_runtime.h>
#include <hip/hip_bf16.h>
#include <math.h>

#define NBANDS 400
#define NPIX   65536
#define FFW    128
#define KSEL   10
#define TOK    16    // tokens per WG
#define HS     403   // h LDS row stride (doubles)
#define FS     131   // f LDS row stride (doubles)

typedef double f64x4 __attribute__((ext_vector_type(4)));
#define MFMA64(a,b,c) __builtin_amdgcn_mfma_f64_16x16x4f64((a),(b),(c),0,0,0)

// ---- ws byte offsets ----
static constexpr size_t WSB_WVOT = 0;          // fp64 [2][400][400]  WvoT[l][k][j] = (Wo@Wv)[j][k]
static constexpr size_t WSB_BVO  = 2560000;    // fp64 [2][400]       Wo@bv + bo
static constexpr size_t WSB_SIG  = 2566400;    // fp64 [400]          sigmoid(band_importance)
static constexpr size_t WSB_W1T  = 2569600;    // fp32 [2][400][128]  W1T[l][k][jf] = W1[l][jf][k]
static constexpr size_t WSB_W2T  = 2979200;    // fp32 [2][128][400]  W2T[l][kf][j] = W2[l][j][kf]
static constexpr size_t WS_NEED  = 3388800;

// ---- out offsets (fp32 elements) ----
static constexpr size_t REC_OFF = 0;
static constexpr size_t IDX_OFF = 26214400;             // 400*65536
static constexpr size_t SCO_OFF = IDX_OFF + 655360;     // + 65536*10
static constexpr size_t SEL_OFF = SCO_OFF + 26214400;
static constexpr int    OUT_EXPECT = 53739520;

// ---------------- prep kernels ----------------

__global__ void prep_wvot(const float* __restrict__ Wv, const float* __restrict__ Wo,
                          double* __restrict__ WvoT) {
    int b = blockIdx.x;              // l*400 + j
    int l = b / 400, j = b - l * 400;
    int k = threadIdx.x;
    if (k >= 400) return;
    const float* wo = Wo + l * 160000 + j * 400;
    const float* wv = Wv + l * 160000;
    double acc = 0.0;
    #pragma unroll 4
    for (int m = 0; m < 400; ++m)
        acc += (double)wo[m] * (double)wv[m * 400 + k];
    WvoT[l * 160000 + k * 400 + j] = acc;
}

__global__ void prep_transpose(const float* __restrict__ W1, const float* __restrict__ W2,
                               float* __restrict__ W1T, float* __restrict__ W2T) {
    int idx = blockIdx.x * blockDim.x + threadIdx.x;
    if (idx < 2 * FFW * NBANDS) {
        int l = idx / (FFW * NBANDS); int r = idx - l * (FFW * NBANDS);
        int jf = r / NBANDS; int k = r - jf * NBANDS;
        W1T[l * FFW * NBANDS + k * FFW + jf] = W1[idx];      // exact value copy
        int j = r / FFW; int kf = r - j * FFW;
        W2T[l * FFW * NBANDS + kf * NBANDS + j] = W2[idx];   // exact value copy
    }
}

__global__ void prep_small(const float* __restrict__ Wo, const float* __restrict__ bv,
                           const float* __restrict__ bo, const float* __restrict__ bi,
                           double* __restrict__ bvo, double* __restrict__ sigd) {
    int g = blockIdx.x * blockDim.x + threadIdx.x;
    if (g < 800) {
        int l = g / 400;
        const float* wo = Wo + l * 160000 + (g - l * 400) * 400;
        const float* bb = bv + l * 400;
        double acc = (double)bo[g];
        for (int m = 0; m < 400; ++m) acc += (double)wo[m] * (double)bb[m];
        bvo[g] = acc;
    } else if (g < 1200) {
        int c = g - 800;
        sigd[c] = 1.0 / (1.0 + exp(-(double)bi[c]));
    }
}

__global__ void sentinel_kernel(float* out, float v) {
    out[blockIdx.x * 256 + threadIdx.x] = v;   // diagnostic marker
}

// ---------------- main kernel ----------------
// r8 structure exactly (16 tokens/WG, 512 threads = 8 waves, 2 WGs/CU,
// MFMA f64 16x16x4, D-slots self-calibrated). ONE change: all streaming
// traffic (x load, xo gather, all 4 output stores) uses non-temporal
// load/store so the ~3.4 MB weight panel stays L2-resident instead of being
// evicted by 105 MB x-reads + 210 MB output-writes (r8 FETCH showed ~25x
// weight re-fetch from HBM -> ~900cyc B-load stalls in the k-loops).
// LDS dbl: h 16*403=6448, f 16*131=2096, red 64, lval 160, sigs 400,
// d1s 72(eq), lidx 80(eq) => 74560 B -> 2 WGs/CU.

__device__ inline void layer_norm_inplace(double* __restrict__ h, double* __restrict__ red,
                                          const float* __restrict__ w, const float* __restrict__ b,
                                          int tid) {
    {
        int t = tid >> 5, q = tid & 31;       // 16 tokens x 32 lanes
        double s = 0.0, ss = 0.0;
        for (int j = q; j < NBANDS; j += 32) {
            double v = h[t * HS + j]; s += v; ss += v * v;
        }
        #pragma unroll
        for (int m = 1; m < 32; m <<= 1) {
            s  += __shfl_xor(s, m, 64);
            ss += __shfl_xor(ss, m, 64);
        }
        if (q == 0) { red[t * 2] = s; red[t * 2 + 1] = ss; }
    }
    __syncthreads();
    for (int idx = tid; idx < TOK * NBANDS; idx += 512) {
        int t = idx / NBANDS, j = idx - t * NBANDS;
        double mu  = red[t * 2] / 400.0;
        double var = red[t * 2 + 1] / 400.0 - mu * mu;
        double rs  = 1.0 / sqrt(var + 1e-5);
        h[t * HS + j] = (h[t * HS + j] - mu) * rs * (double)w[j] + (double)b[j];
    }
    __syncthreads();
}

__global__ __launch_bounds__(512) void hbsm_main(
    const float* __restrict__ x, const float* __restrict__ xo,
    const float* __restrict__ pos,
    const float* __restrict__ ln1w, const float* __restrict__ ln1b,
    const float* __restrict__ b1,   const float* __restrict__ b2,
    const float* __restrict__ ln2w, const float* __restrict__ ln2b,
    const float* __restrict__ We1,  const float* __restrict__ be1,
    const float* __restrict__ We2,  const float* __restrict__ be2,
    const float* __restrict__ Wd1,  const float* __restrict__ bd1,
    const float* __restrict__ Wd2,  const float* __restrict__ bd2,
    const double* __restrict__ WvoT, const double* __restrict__ bvo,
    const double* __restrict__ sigd,
    const float* __restrict__ W1Tf,  const float* __restrict__ W2Tf,
    float* __restrict__ out)
{
    extern __shared__ double smem[];
    double* h    = smem;                    // 16*403
    double* f    = h + TOK * HS;            // 16*131
    double* red  = f + TOK * FS;            // 64
    double* lval = red + 64;                // 160
    double* sigs = lval + 160;              // 400
    float*  d1s  = (float*)(sigs + 400);    // 144 f32
    int*    lidx = (int*)(d1s + 144);       // 160 i32

    const int tid  = threadIdx.x;
    const int p0   = blockIdx.x * TOK;
    const int lane = tid & 63;
    const int wv   = tid >> 6;              // wave 0..7
    const int rA   = lane & 15;             // A-load row / B-load col
    const int kq   = lane >> 4;             // k quarter (assumed, cancels if wrong)

    // ---- D-slot self-calibration ----
    int rowm[4], colm[4];
    {
        f64x4 z = {0.0, 0.0, 0.0, 0.0};
        f64x4 pr = MFMA64(0.25 * (double)rA, 1.0, z);   // D[i][j] = i
        f64x4 pc = MFMA64(0.25, (double)rA, z);         // D[i][j] = j
        #pragma unroll
        for (int i = 0; i < 4; ++i) {
            rowm[i] = ((int)(pr[i] + 0.5)) & 15;
            colm[i] = ((int)(pc[i] + 0.5)) & 15;
        }
    }

    for (int i = tid; i < NBANDS; i += 512) sigs[i] = sigd[i];
    for (int i = tid; i < TOK * NBANDS; i += 512) {
        int t = i & 15, c = i >> 4;
        float xv = __builtin_nontemporal_load(&x[(size_t)c * NPIX + p0 + t]);
        h[t * HS + c] = (double)xv + (double)pos[c];
    }
    __syncthreads();

    const double* hA = h + rA * HS;
    const int c0 = wv * 16 + rA, c1 = c0 + 128, c2 = c0 + 256;
    const int ct = 384 + rA;
    const bool xtraA = (wv == 0);           // attn tail tile owner
    const bool xtraF = (wv == 4);           // FF2 tail tile owner

    for (int l = 0; l < 2; ++l) {
        // ---- attention: h += h @ WvoT + bvo ; LN1 ----
        {
            const double* WT  = WvoT + l * 160000;
            const double* bb0 = bvo + l * 400;
            f64x4 a0={0,0,0,0}, a1={0,0,0,0}, a2={0,0,0,0}, a3={0,0,0,0};
            #pragma unroll 2
            for (int k0 = 0; k0 < NBANDS; k0 += 4) {
                double av = hA[k0 + kq];
                const double* wrow = WT + (size_t)(k0 + kq) * 400;
                a0 = MFMA64(av, wrow[c0], a0);
                a1 = MFMA64(av, wrow[c1], a1);
                a2 = MFMA64(av, wrow[c2], a2);
                if (xtraA) a3 = MFMA64(av, wrow[ct], a3);
            }
            __syncthreads();      // all A-reads of h complete before in-place update
            #pragma unroll
            for (int i = 0; i < 4; ++i) {
                int r  = rowm[i];
                int j0 = wv * 16 + colm[i], j1 = j0 + 128, j2 = j0 + 256;
                h[r * HS + j0] += a0[i] + bb0[j0];
                h[r * HS + j1] += a1[i] + bb0[j1];
                h[r * HS + j2] += a2[i] + bb0[j2];
                if (xtraA) {
                    int jt = 384 + colm[i];
                    h[r * HS + jt] += a3[i] + bb0[jt];
                }
            }
            __syncthreads();
        }
        layer_norm_inplace(h, red, ln1w + l * 400, ln1b + l * 400, tid);

        // ---- FF1: f = relu(h @ W1T + b1)  (N=128: wave w -> col-tile w) ----
        {
            const float* WT  = W1Tf + (size_t)l * 51200;
            const float* bb1 = b1 + l * FFW;
            const int cf = wv * 16 + rA;
            f64x4 e0 = {0,0,0,0};
            #pragma unroll 2
            for (int k0 = 0; k0 < NBANDS; k0 += 4) {
                double av = hA[k0 + kq];
                double b = (double)WT[(size_t)(k0 + kq) * FFW + cf];
                e0 = MFMA64(av, b, e0);
            }
            #pragma unroll
            for (int i = 0; i < 4; ++i) {
                int r  = rowm[i];
                int jf = wv * 16 + colm[i];
                double v0 = e0[i] + (double)bb1[jf];
                f[r * FS + jf] = v0 > 0.0 ? v0 : 0.0;
            }
            __syncthreads();   // f writes visible (also fences FF1's h reads)
        }

        // ---- FF2: h += f @ W2T + b2 ; LN2 ----
        {
            const float* WT  = W2Tf + (size_t)l * 51200;
            const float* bb2 = b2 + l * 400;
            const double* fA = f + rA * FS;
            f64x4 a0={0,0,0,0}, a1={0,0,0,0}, a2={0,0,0,0}, a3={0,0,0,0};
            #pragma unroll 2
            for (int k0 = 0; k0 < FFW; k0 += 4) {
                double av = fA[k0 + kq];
                const float* wrow = WT + (size_t)(k0 + kq) * 400;
                a0 = MFMA64(av, (double)wrow[c0], a0);
                a1 = MFMA64(av, (double)wrow[c1], a1);
                a2 = MFMA64(av, (double)wrow[c2], a2);
                if (xtraF) a3 = MFMA64(av, (double)wrow[ct], a3);
            }
            // h is not read during FF2 (A comes from f); owner-disjoint writes safe
            #pragma unroll
            for (int i = 0; i < 4; ++i) {
                int r  = rowm[i];
                int j0 = wv * 16 + colm[i], j1 = j0 + 128, j2 = j0 + 256;
                h[r * HS + j0] += a0[i] + (double)bb2[j0];
                h[r * HS + j1] += a1[i] + (double)bb2[j1];
                h[r * HS + j2] += a2[i] + (double)bb2[j2];
                if (xtraF) {
                    int jt = 384 + colm[i];
                    h[r * HS + jt] += a3[i] + (double)bb2[jt];
                }
            }
            __syncthreads();
        }
        layer_norm_inplace(h, red, ln2w + l * 400, ln2b + l * 400, tid);
    }

    // ---- attention scores output (fp32, NT stores) ----
    for (int idx = tid; idx < TOK * NBANDS; idx += 512) {
        int t = idx / NBANDS, c = idx - t * NBANDS;
        __builtin_nontemporal_store((float)(h[t * HS + c] * sigs[c]),
                                    &out[SCO_OFF + (size_t)(p0 + t) * NBANDS + c]);
    }

    // ---- top-k, gather, encoder/decoder front (1 thread per token) ----
    if (tid < TOK) {
        int t = tid;
        double* lv = lval + t * KSEL;
        int*    li = lidx + t * KSEL;
        #pragma unroll
        for (int k = 0; k < KSEL; ++k) { lv[k] = -1.0e300; li[k] = 0; }
        for (int c = 0; c < NBANDS; ++c) {
            double v = h[t * HS + c] * sigs[c];
            if (v > lv[KSEL - 1]) {           // strict > keeps earlier index on ties
                int j = KSEL - 1;
                while (j > 0 && lv[j - 1] < v) {
                    lv[j] = lv[j - 1]; li[j] = li[j - 1]; --j;
                }
                lv[j] = v; li[j] = c;
            }
        }
        for (int a = 1; a < KSEL; ++a) {      // sort by band index ascending
            double v = lv[a]; int ci = li[a];
            int bq = a - 1;
            while (bq >= 0 && li[bq] > ci) {
                lv[bq + 1] = lv[bq]; li[bq + 1] = li[bq]; --bq;
            }
            lv[bq + 1] = v; li[bq + 1] = ci;
        }
        double sel[KSEL];
        #pragma unroll
        for (int k = 0; k < KSEL; ++k) {
            int ci = li[k];
            float band = __builtin_nontemporal_load(&xo[(size_t)ci * NPIX + p0 + t]);
            __builtin_nontemporal_store((float)ci,
                &out[IDX_OFF + (size_t)(p0 + t) * KSEL + k]);
            __builtin_nontemporal_store(band,
                &out[SEL_OFF + (size_t)(p0 + t) * KSEL + k]);
            sel[k] = (double)band * lv[k];
        }
        double e1[8], e2[8];
        #pragma unroll
        for (int e = 0; e < 8; ++e) {
            double acc = (double)be1[e];
            #pragma unroll
            for (int k = 0; k < KSEL; ++k) acc += sel[k] * (double)We1[e * KSEL + k];
            e1[e] = acc > 0.0 ? acc : 0.0;
        }
        #pragma unroll
        for (int e = 0; e < 8; ++e) {
            double acc = (double)be2[e];
            #pragma unroll
            for (int j = 0; j < 8; ++j) acc += e1[j] * (double)We2[e * 8 + j];
            e2[e] = acc;
        }
        #pragma unroll
        for (int e = 0; e < 8; ++e) {
            double acc = (double)bd1[e];
            #pragma unroll
            for (int j = 0; j < 8; ++j) acc += e2[j] * (double)Wd1[e * 8 + j];
            d1s[t * 9 + e] = (float)(acc > 0.0 ? acc : 0.0);
        }
    }
    __syncthreads();

    // ---- decode + reconstructed output (fp32, NT stores) ----
    for (int idx = tid; idx < TOK * NBANDS; idx += 512) {
        int t = idx & 15, c = idx >> 4;
        double acc = (double)bd2[c];
        const float* w = Wd2 + c * 8;
        #pragma unroll
        for (int e = 0; e < 8; ++e) acc += (double)d1s[t * 9 + e] * (double)w[e];
        __builtin_nontemporal_store((float)acc,
                                    &out[REC_OFF + (size_t)c * NPIX + p0 + t]);
    }
}

// ---------------- launch ----------------
extern "C" void kernel_launch(void* const* d_in, const int* in_sizes, int n_in,
                              void* d_out, int out_size, void* d_ws, size_t ws_size,
                              hipStream_t stream) {
    if (ws_size < WS_NEED) {   // diagnostic: ws too small -> error ~777
        sentinel_kernel<<<dim3(256), dim3(256), 0, stream>>>((float*)d_out, -777.0f);
        return;
    }
    if (out_size != OUT_EXPECT) {  // diagnostic: unexpected out layout -> error ~1e6
        sentinel_kernel<<<dim3(1), dim3(1), 0, stream>>>((float*)d_out, 1.0e6f);
        return;
    }
    const float* x    = (const float*)d_in[0];
    const float* xo   = (const float*)d_in[1];
    const float* pos  = (const float*)d_in[2];
    const float* bi   = (const float*)d_in[3];
    const float* Wv   = (const float*)d_in[4];
    const float* bv   = (const float*)d_in[5];
    const float* Wo   = (const float*)d_in[6];
    const float* bo   = (const float*)d_in[7];
    const float* ln1w = (const float*)d_in[8];
    const float* ln1b = (const float*)d_in[9];
    const float* W1   = (const float*)d_in[10];
    const float* b1   = (const float*)d_in[11];
    const float* W2   = (const float*)d_in[12];
    const float* b2   = (const float*)d_in[13];
    const float* ln2w = (const float*)d_in[14];
    const float* ln2b = (const float*)d_in[15];
    const float* We1  = (const float*)d_in[16];
    const float* be1  = (const float*)d_in[17];
    const float* We2  = (const float*)d_in[18];
    const float* be2  = (const float*)d_in[19];
    const float* Wd1  = (const float*)d_in[20];
    const float* bd1  = (const float*)d_in[21];
    const float* Wd2  = (const float*)d_in[22];
    const float* bd2  = (const float*)d_in[23];

    char* wsb = (char*)d_ws;
    double* WvoT = (double*)(wsb + WSB_WVOT);
    double* bvo  = (double*)(wsb + WSB_BVO);
    double* sigd = (double*)(wsb + WSB_SIG);
    float*  W1Tf = (float*)(wsb + WSB_W1T);
    float*  W2Tf = (float*)(wsb + WSB_W2T);

    prep_wvot<<<dim3(800), dim3(512), 0, stream>>>(Wv, Wo, WvoT);
    prep_transpose<<<dim3(400), dim3(256), 0, stream>>>(W1, W2, W1Tf, W2Tf);
    prep_small<<<dim3(5), dim3(256), 0, stream>>>(Wo, bv, bo, bi, bvo, sigd);

    const int smem_bytes = 74560;
    hipFuncSetAttribute((const void*)hbsm_main,
                        hipFuncAttributeMaxDynamicSharedMemorySize, smem_bytes);
    hipLaunchKernelGGL(hbsm_main, dim3(4096), dim3(512), smem_bytes, stream,
                       x, xo, pos, ln1w, ln1b, b1, b2, ln2w, ln2b,
                       We1, be1, We2, be2, Wd1, bd1, Wd2, bd2,
                       WvoT, bvo, sigd, W1Tf, W2Tf, (float*)d_out);
    (void)in_sizes; (void)n_in;
}